// Round 8
// baseline (342.684 us; speedup 1.0000x reference)
//
#include <hip/hip_runtime.h>

#define N_TOK 4096
#define RD 64
#define CDIM 256

typedef __bf16 bf16x8 __attribute__((ext_vector_type(8)));
typedef float f32x4 __attribute__((ext_vector_type(4)));
typedef unsigned short u16;
typedef unsigned int u32;
typedef u32 u32x2 __attribute__((ext_vector_type(2)));
typedef short s16x4 __attribute__((ext_vector_type(4)));

__device__ __forceinline__ u16 f2bf(float f) {
  u32 u = __float_as_uint(f);
  u = (u + 0x7fffu + ((u >> 16) & 1u)) >> 16;  // RNE
  return (u16)u;
}

__device__ __forceinline__ u32 pack2bf(float a, float b) {
  u16 ha = __builtin_bit_cast(u16, (__bf16)a);
  u16 hb = __builtin_bit_cast(u16, (__bf16)b);
  return (u32)ha | ((u32)hb << 16);
}

__device__ __forceinline__ f32x4 zero4() {
  f32x4 z = {0.f, 0.f, 0.f, 0.f};
  return z;
}

// 16x16x16 bf16 MFMA (K=16): A-frag row=l15, k=(lane>>4)*4+e == swapped-QK^T
// D-frag layout -> softmaxed s[] feeds the A operand directly (no exchange).
__device__ __forceinline__ f32x4 mfma16bf(u32x2 a, u32x2 b, f32x4 c) {
#if __has_builtin(__builtin_amdgcn_mfma_f32_16x16x16bf16_1k)
  return __builtin_amdgcn_mfma_f32_16x16x16bf16_1k(
      __builtin_bit_cast(s16x4, a), __builtin_bit_cast(s16x4, b), c, 0, 0, 0);
#else
  f32x4 d = c;
  asm("v_mfma_f32_16x16x16_bf16 %0, %1, %2, %0" : "+v"(d) : "v"(a), "v"(b));
  return d;
#endif
}

// Explicit vmcnt drain: the dbuf handoff must NOT rely on the compiler
// emitting vmcnt(0) at __syncthreads (r7 intermittent-divergence root cause —
// global_load_lds prefetch still in flight when another wave crossed barrier).
#define DRAIN_VMCNT() asm volatile("s_waitcnt vmcnt(0)" ::: "memory")

// ---------------------------------------------------------------------------
// Projection (unchanged): out[n][o] = sum_c W[o][c] * X[b][c][n]
// ---------------------------------------------------------------------------
__global__ __launch_bounds__(256) void proj_kernel(
    const float* __restrict__ wli, const float* __restrict__ nbi,
    const float* __restrict__ wq0, const float* __restrict__ wk0,
    const float* __restrict__ wv0, const float* __restrict__ wq1,
    const float* __restrict__ wk1, const float* __restrict__ wv1,
    u16* __restrict__ Qb, u16* __restrict__ Kb, u16* __restrict__ Vb) {
  extern __shared__ char smem[];
  const int ntile = blockIdx.x, bb = blockIdx.y, pid = blockIdx.z;
  const int tid = threadIdx.x;
  const int w = tid >> 6, lane = tid & 63, g = lane >> 4, l15 = lane & 15;
  const int n0 = ntile * 64;

  const float* X;
  const float* W;
  u16* out;
  float scale = 1.f;
  int form, nchunk;
  switch (pid) {
    case 0: X = wli; W = wq0; out = Qb + (size_t)(0 + bb) * N_TOK * RD; scale = 0.125f; form = 1; nchunk = 1; break;
    case 1: X = nbi; W = wk0; out = Kb + (size_t)(0 + bb) * N_TOK * RD; form = 1; nchunk = 1; break;
    case 2: X = nbi; W = wv0; out = Vb + (size_t)(0 + bb) * CDIM * N_TOK; form = 2; nchunk = 4; break;
    case 3: X = nbi; W = wq1; out = Qb + (size_t)(4 + bb) * N_TOK * RD; scale = 0.125f; form = 1; nchunk = 1; break;
    case 4: X = wli; W = wk1; out = Kb + (size_t)(4 + bb) * N_TOK * RD; form = 1; nchunk = 1; break;
    default: X = wli; W = wv1; out = Vb + (size_t)(4 + bb) * CDIM * N_TOK; form = 2; nchunk = 4; break;
  }
  X += (size_t)bb * CDIM * N_TOK;

#pragma unroll
  for (int rep = 0; rep < 16; ++rep) {
    int idx = rep * 256 + tid;
    int c = idx >> 4;
    int nq = (idx & 15) * 4;
    float4 v = *(const float4*)(X + (size_t)c * N_TOK + n0 + nq);
    float vv[4] = {v.x, v.y, v.z, v.w};
#pragma unroll
    for (int k = 0; k < 4; ++k) {
      int row = nq + k;
      int addr = (row * 512 + c * 2) ^ ((row & 7) << 4);
      *(u16*)(smem + addr) = f2bf(vv[k] * scale);
    }
  }

  for (int oc = 0; oc < nchunk; ++oc) {
#pragma unroll
    for (int rep = 0; rep < 16; ++rep) {
      int idx = rep * 256 + tid;
      int o = idx >> 6;
      int c4 = (idx & 63) * 4;
      float4 v = *(const float4*)(W + (size_t)(oc * 64 + o) * CDIM + c4);
      ushort4 pk = {f2bf(v.x), f2bf(v.y), f2bf(v.z), f2bf(v.w)};
      int addr = 32768 + ((o * 512 + c4 * 2) ^ ((o & 7) << 4));
      *(ushort4*)(smem + addr) = pk;
    }
    __syncthreads();

    f32x4 acc[4];
#pragma unroll
    for (int ct = 0; ct < 4; ++ct) acc[ct] = zero4();
    const int arow = w * 16 + l15;
    const int abase = (form == 1) ? 0 : 32768;
    const int bbase = (form == 1) ? 32768 : 0;
#pragma unroll
    for (int kk = 0; kk < 8; ++kk) {
      int koff = kk * 64 + g * 16;
      bf16x8 af = *(const bf16x8*)(smem + abase + ((arow * 512 + koff) ^ ((arow & 7) << 4)));
#pragma unroll
      for (int ct = 0; ct < 4; ++ct) {
        int brow = ct * 16 + l15;
        bf16x8 bfr = *(const bf16x8*)(smem + bbase + ((brow * 512 + koff) ^ ((brow & 7) << 4)));
        acc[ct] = __builtin_amdgcn_mfma_f32_16x16x32_bf16(af, bfr, acc[ct], 0, 0, 0);
      }
    }
    if (form == 1) {
#pragma unroll
      for (int ct = 0; ct < 4; ++ct)
#pragma unroll
        for (int r = 0; r < 4; ++r)
          out[(size_t)(n0 + w * 16 + g * 4 + r) * RD + ct * 16 + l15] = f2bf(acc[ct][r]);
    } else {
#pragma unroll
      for (int ct = 0; ct < 4; ++ct)
#pragma unroll
        for (int r = 0; r < 4; ++r)
          out[(size_t)(oc * 64 + w * 16 + g * 4 + r) * N_TOK + n0 + ct * 16 + l15] = f2bf(acc[ct][r]);
    }
    __syncthreads();
  }
}

// ---------------------------------------------------------------------------
// Flash attention + residual, 2-phase pipeline, quadrant wave mapping.
// Waves: wq=w>>1 (q-half: 32 rows), wc=w&1 (c-half: 128 cols).
// V B-fragments reused across the wave's 2 q-tiles (halves V LDS reads);
// PV uses K=16 MFMA so s[] IS the A-fragment (no P exchange at all).
// LDS (80KB): buf[2] x { K 8KB | V 32KB }, staged via global_load_lds(16B)
// with pre-swizzled global source (byte ^= (row&7)<<4 on 16B chunks).
// Explicit s_waitcnt vmcnt(0) before every barrier (dbuf handoff safety).
// grid 1-D 512; inst = wgid&7 clusters each instance on one XCD.
// ---------------------------------------------------------------------------
__global__ __launch_bounds__(256, 2) void attn_kernel(
    const u16* __restrict__ Qb, const u16* __restrict__ Kb,
    const u16* __restrict__ Vb, const float* __restrict__ x_wli,
    const float* __restrict__ x_nbi, float* __restrict__ y) {
  extern __shared__ char smem[];
  const int wgid = blockIdx.x;
  const int inst = wgid & 7;
  const int ntile = wgid >> 3;
  const int br = inst >> 2, bb = inst & 3;
  const int tid = threadIdx.x;
  const int w = tid >> 6, lane = tid & 63, g = lane >> 4, l15 = lane & 15;
  const int wq = w >> 1, wc = w & 1;
  const u16* Q = Qb + (size_t)inst * N_TOK * RD + (size_t)ntile * 64 * RD;
  const u16* K = Kb + (size_t)inst * N_TOK * RD;
  const u16* Vt = Vb + (size_t)inst * CDIM * N_TOK;
  const float* xres = (br == 0 ? x_wli : x_nbi) + (size_t)bb * CDIM * N_TOK;
  float* yout = y + (size_t)inst * CDIM * N_TOK;

  // Q fragments: 2 q-tiles (wq*32 + qt*16), 2 K=32 k-chunks each
  bf16x8 qf[2][2];
#pragma unroll
  for (int qt = 0; qt < 2; ++qt) {
    const u16* qrow = Q + (wq * 32 + qt * 16 + l15) * RD;
    qf[qt][0] = *(const bf16x8*)(qrow + g * 8);
    qf[qt][1] = *(const bf16x8*)(qrow + 32 + g * 8);
  }
  f32x4 o_acc[2][8];
#pragma unroll
  for (int qt = 0; qt < 2; ++qt)
#pragma unroll
    for (int ct = 0; ct < 8; ++ct) o_acc[qt][ct] = zero4();
  float m_ln[2] = {-1e30f, -1e30f}, l_ln[2] = {0.f, 0.f};
  const float LOG2E = 1.44269504088896340736f;

#define STAGE_KV(kv0_, boff_)                                                    \
  {                                                                              \
    _Pragma("unroll") for (int rr = 0; rr < 2; ++rr) {                           \
      int s_ = w * 128 + rr * 64 + lane;                                         \
      int j = s_ >> 3, c16 = s_ & 7;                                             \
      const u16* gp = K + (size_t)((kv0_) + j) * RD + ((c16 ^ (j & 7)) * 8);     \
      char* lp = smem + (boff_) + (w * 128 + rr * 64) * 16;                      \
      __builtin_amdgcn_global_load_lds(                                          \
          (const __attribute__((address_space(1))) void*)gp,                     \
          (__attribute__((address_space(3))) void*)lp, 16, 0, 0);                \
    }                                                                            \
    _Pragma("unroll") for (int rr = 0; rr < 8; ++rr) {                           \
      int s_ = w * 512 + rr * 64 + lane;                                         \
      int c = s_ >> 3, c16 = s_ & 7;                                             \
      const u16* gp = Vt + (size_t)c * N_TOK + (kv0_) + ((c16 ^ (c & 7)) * 8);   \
      char* lp = smem + (boff_) + 8192 + (w * 512 + rr * 64) * 16;               \
      __builtin_amdgcn_global_load_lds(                                          \
          (const __attribute__((address_space(1))) void*)gp,                     \
          (__attribute__((address_space(3))) void*)lp, 16, 0, 0);                \
    }                                                                            \
  }

  STAGE_KV(0, 0);
  DRAIN_VMCNT();
  __syncthreads();

  for (int t = 0; t < 64; ++t) {
    const int kv0 = t * 64;
    const int bufOff = (t & 1) * 40960;
    if (t < 63) STAGE_KV(kv0 + 64, ((t + 1) & 1) * 40960);

    // S^T = K . Q^T for both q-tiles (K fragments shared)
    f32x4 s[2][4];
#pragma unroll
    for (int jt = 0; jt < 4; ++jt) {
      int row = jt * 16 + l15;
      int a0 = bufOff + ((row * 128 + g * 16) ^ ((row & 7) << 4));
      int a1 = bufOff + ((row * 128 + 64 + g * 16) ^ ((row & 7) << 4));
      bf16x8 kf0 = *(const bf16x8*)(smem + a0);
      bf16x8 kf1 = *(const bf16x8*)(smem + a1);
#pragma unroll
      for (int qt = 0; qt < 2; ++qt) {
        f32x4 acc = __builtin_amdgcn_mfma_f32_16x16x32_bf16(kf0, qf[qt][0], zero4(), 0, 0, 0);
        s[qt][jt] = __builtin_amdgcn_mfma_f32_16x16x32_bf16(kf1, qf[qt][1], acc, 0, 0, 0);
      }
    }

    // online softmax per q-tile, defer-max (THR=8)
    float mx[2];
#pragma unroll
    for (int qt = 0; qt < 2; ++qt) {
      float m = s[qt][0][0];
#pragma unroll
      for (int jt = 0; jt < 4; ++jt)
#pragma unroll
        for (int r = 0; r < 4; ++r) m = fmaxf(m, s[qt][jt][r]);
      m = fmaxf(m, __shfl_xor(m, 16));
      m = fmaxf(m, __shfl_xor(m, 32));
      mx[qt] = m;
    }
    if (!__all(mx[0] - m_ln[0] <= 8.f && mx[1] - m_ln[1] <= 8.f)) {
#pragma unroll
      for (int qt = 0; qt < 2; ++qt) {
        float mnew = fmaxf(m_ln[qt], mx[qt]);
        float corr = exp2f((m_ln[qt] - mnew) * LOG2E);
        m_ln[qt] = mnew;
        l_ln[qt] *= corr;
        float corrO[4];
#pragma unroll
        for (int r = 0; r < 4; ++r) corrO[r] = __shfl(corr, (lane & 48) | (g * 4 + r));
#pragma unroll
        for (int ct = 0; ct < 8; ++ct)
#pragma unroll
          for (int r = 0; r < 4; ++r) o_acc[qt][ct][r] *= corrO[r];
      }
    }
#pragma unroll
    for (int qt = 0; qt < 2; ++qt) {
      float sum = 0.f;
#pragma unroll
      for (int jt = 0; jt < 4; ++jt)
#pragma unroll
        for (int r = 0; r < 4; ++r) {
          float p = exp2f((s[qt][jt][r] - m_ln[qt]) * LOG2E);
          s[qt][jt][r] = p;
          sum += p;
        }
      sum += __shfl_xor(sum, 16);
      sum += __shfl_xor(sum, 32);
      l_ln[qt] += sum;
    }

    // pack P to bf16: s[qt][jt] IS the K=16 A-fragment for j-block jt
    u32x2 pa[2][4];
#pragma unroll
    for (int qt = 0; qt < 2; ++qt)
#pragma unroll
      for (int jt = 0; jt < 4; ++jt) {
        u32x2 v;
        v[0] = pack2bf(s[qt][jt][0], s[qt][jt][1]);
        v[1] = pack2bf(s[qt][jt][2], s[qt][jt][3]);
        pa[qt][jt] = v;
      }

    // PV: O[q][c] += P[q][j] V[j][c], K=16 MFMA; V b64 shared across q-tiles
    __builtin_amdgcn_s_setprio(1);
    const int vb = bufOff + 8192;
#pragma unroll
    for (int ct = 0; ct < 8; ++ct) {
      int c = wc * 128 + ct * 16 + l15;
      int cbase = c * 128;
      int cswz = (c & 7) << 4;
#pragma unroll
      for (int jt = 0; jt < 4; ++jt) {
        int addr = vb + ((cbase + jt * 32 + g * 8) ^ cswz);
        u32x2 vfr = *(const u32x2*)(smem + addr);
        o_acc[0][ct] = mfma16bf(pa[0][jt], vfr, o_acc[0][ct]);
        o_acc[1][ct] = mfma16bf(pa[1][jt], vfr, o_acc[1][ct]);
      }
    }
    __builtin_amdgcn_s_setprio(0);
    DRAIN_VMCNT();      // architectural guarantee: prefetch landed before swap
    __syncthreads();
  }

  // epilogue: y = x + O/l   (y layout (br,b,c,n))
#pragma unroll
  for (int qt = 0; qt < 2; ++qt) {
    float rl = 1.f / l_ln[qt];
    float rlO[4];
#pragma unroll
    for (int r = 0; r < 4; ++r) rlO[r] = __shfl(rl, (lane & 48) | (g * 4 + r));
    const int nbase = ntile * 64 + wq * 32 + qt * 16;
#pragma unroll
    for (int ct = 0; ct < 8; ++ct) {
      int c = wc * 128 + ct * 16 + l15;
#pragma unroll
      for (int r = 0; r < 4; ++r) {
        size_t idx = (size_t)c * N_TOK + nbase + g * 4 + r;
        yout[idx] = xres[idx] + o_acc[qt][ct][r] * rlO[r];
      }
    }
  }
#undef STAGE_KV
}

// ---------------------------------------------------------------------------
// BN stats: one block per (branch, channel); mean + rsqrt(var+eps) over 16384
// ---------------------------------------------------------------------------
__global__ __launch_bounds__(256) void bn_stats_kernel(const float* __restrict__ y,
                                                       float* __restrict__ stats) {
  const int idx = blockIdx.x;  // branch*256 + c
  const int br = idx >> 8, c = idx & 255;
  const float* base = y + (size_t)br * 4 * CDIM * N_TOK + (size_t)c * N_TOK;
  float s1 = 0.f, s2 = 0.f;
#pragma unroll
  for (int bb = 0; bb < 4; ++bb) {
    const float* p = base + (size_t)bb * CDIM * N_TOK;
    for (int off = threadIdx.x * 4; off < N_TOK; off += 1024) {
      float4 v = *(const float4*)(p + off);
      s1 += v.x + v.y + v.z + v.w;
      s2 += v.x * v.x + v.y * v.y + v.z * v.z + v.w * v.w;
    }
  }
#pragma unroll
  for (int msk = 1; msk < 64; msk <<= 1) {
    s1 += __shfl_xor(s1, msk);
    s2 += __shfl_xor(s2, msk);
  }
  __shared__ float a1[4], a2[4];
  const int wv = threadIdx.x >> 6, ln = threadIdx.x & 63;
  if (ln == 0) { a1[wv] = s1; a2[wv] = s2; }
  __syncthreads();
  if (threadIdx.x == 0) {
    float t1 = a1[0] + a1[1] + a1[2] + a1[3];
    float t2 = a2[0] + a2[1] + a2[2] + a2[3];
    float mean = t1 * (1.f / 16384.f);
    float var = t2 * (1.f / 16384.f) - mean * mean;
    stats[idx] = mean;
    stats[512 + idx] = rsqrtf(var + 1e-5f);
  }
}

__global__ __launch_bounds__(256) void bn_apply_kernel(
    const float* __restrict__ y, const float* __restrict__ stats,
    const float* __restrict__ g0, const float* __restrict__ b0,
    const float* __restrict__ g1, const float* __restrict__ b1,
    float* __restrict__ out) {
  size_t i4 = (size_t)blockIdx.x * 256 + threadIdx.x;  // 2M float4s
  int br = (int)(i4 >> 20);
  int c = (int)(i4 >> 10) & 255;
  float mean = stats[br * 256 + c];
  float rstd = stats[512 + br * 256 + c];
  float ga = (br ? g1 : g0)[c];
  float be = (br ? b1 : b0)[c];
  float a = rstd * ga;
  float4 v = *(const float4*)(y + i4 * 4);
  v.x = (v.x - mean) * a + be;
  v.y = (v.y - mean) * a + be;
  v.z = (v.z - mean) * a + be;
  v.w = (v.w - mean) * a + be;
  *(float4*)(out + i4 * 4) = v;
}

// ---------------------------------------------------------------------------
extern "C" void kernel_launch(void* const* d_in, const int* in_sizes, int n_in,
                              void* d_out, int out_size, void* d_ws, size_t ws_size,
                              hipStream_t stream) {
  const float* wli = (const float*)d_in[0];
  const float* nbi = (const float*)d_in[1];
  const float* wq0 = (const float*)d_in[2];
  const float* wk0 = (const float*)d_in[3];
  const float* wv0 = (const float*)d_in[4];
  const float* wq1 = (const float*)d_in[5];
  const float* wk1 = (const float*)d_in[6];
  const float* wv1 = (const float*)d_in[7];
  const float* g0 = (const float*)d_in[8];
  const float* b0 = (const float*)d_in[9];
  const float* g1 = (const float*)d_in[10];
  const float* b1 = (const float*)d_in[11];

  char* ws = (char*)d_ws;
  u16* Qb = (u16*)(ws + 0);
  u16* Kb = (u16*)(ws + 4194304);
  u16* Vb = (u16*)(ws + 8388608);
  float* y = (float*)(ws + 25165824);
  float* stats = (float*)(ws + 58720256);

  proj_kernel<<<dim3(64, 4, 6), 256, 65536, stream>>>(wli, nbi, wq0, wk0, wv0,
                                                      wq1, wk1, wv1, Qb, Kb, Vb);
  attn_kernel<<<dim3(512), 256, 81920, stream>>>(Qb, Kb, Vb, wli, nbi, y);
  bn_stats_kernel<<<dim3(512), 256, 0, stream>>>(y, stats);
  bn_apply_kernel<<<dim3(8192), 256, 0, stream>>>(y, stats, g0, b0, g1, b1,
                                                  (float*)d_out);
}